// Round 1
// 1025.614 us; speedup vs baseline: 1.5928x; 1.5928x over previous
//
#include <hip/hip_runtime.h>

// Markonv: out[b,n,p] = sum_{l,ij} x[b,i,p+l]*x[b,j,p+l+1] * W[l,i,j,n]
// B=128, C=4, L=10000, K=20, N=128, stride=1, P=9980.
// v2: W is the MFMA A-operand (n in regs, position in lanes) so the epilogue
// writes 128B-contiguous full lines (v1 scattered 16B stores -> 2.3x write
// amplification). Waves split 4-way in n => W frags 80 VGPR (v1: 160, spilled
// to scratch at VGPR_Count=108). Pair tile padded to 48B rows (8-way -> 4-way
// LDS conflicts).
// Roofline: 654 MB fp32 output write => ~104-160 us floor; bf16 MFMA ~42 us.

#define B_    128
#define C_    4
#define L_    10000
#define K_    20
#define N_    128
#define P_    9980          // floor((L-1-K)/1)+1
#define MT    64            // output positions per tile iteration
#define ROWS  (MT + K_ - 1) // 83 pair rows per tile
#define TPG   13            // tiles per workgroup
#define GRPS  12            // tile-groups per batch: 12*13*64 = 9984 >= 9980
#define PSTR  24            // pair row stride in shorts (48 B -> 4-way banks)

typedef float  f32x16 __attribute__((ext_vector_type(16)));
typedef __bf16 bf16x8 __attribute__((ext_vector_type(8)));
typedef unsigned short u16x8 __attribute__((ext_vector_type(8)));

static __device__ __forceinline__ unsigned short f2bf(float f) {
  union { float f; unsigned u; } v; v.f = f;
  unsigned r = (v.u + 0x7fffu + ((v.u >> 16) & 1u)) >> 16;
  return (unsigned short)r;
}

// Repack W[l][i][j][n] fp32 -> Wb[l][n][ij] bf16 (A-fragment friendly: 16
// contiguous bf16 per (l,n) row = one 16B half per lane-half).
__global__ void convW_kernel(const float* __restrict__ W,
                             unsigned short* __restrict__ Wb) {
  int idx = blockIdx.x * 256 + threadIdx.x;          // [l][n][ij]
  if (idx < K_ * N_ * 16) {
    int ij = idx & 15, n = (idx >> 4) & (N_ - 1), l = idx >> 11;
    Wb[idx] = f2bf(W[(l * 16 + ij) * N_ + n]);
  }
}

__launch_bounds__(256, 3)
__global__ void markonv_kernel(const float* __restrict__ x,
                               const unsigned short* __restrict__ Wb,
                               const float* __restrict__ Wf,
                               float* __restrict__ out,
                               int useGather) {
  // LDS: x slab (4 channels x 84 positions) + pair tile (83 rows x 16ch, 48B rows)
  __shared__ __align__(16) float xs[C_][MT + 24];              // 84 used
  __shared__ __align__(16) unsigned short pairLds[ROWS * PSTR];

  const int tid  = threadIdx.x;
  const int lane = tid & 63;
  const int wid  = tid >> 6;        // wave owns n-block: n = wid*32 + ...
  const int h    = lane >> 5;       // k-half
  const int nl   = lane & 31;       // n row within A / position within B col
  const int b    = blockIdx.y;
  const int grp  = blockIdx.x;

  // ---- W fragments (A-operand), 20 x 4 VGPR = 80, resident ----
  // bfr[l]: lane holds W[l][k=8h+j][n = wid*32 + nl], j=0..7
  bf16x8 bfr[K_];
  if (useGather) {
    // fallback: gather straight from fp32 W (ws too small) — slower, correct
    #pragma unroll
    for (int l = 0; l < K_; ++l) {
      int n = wid * 32 + nl;
      u16x8 u;
      #pragma unroll
      for (int j = 0; j < 8; ++j)
        u[j] = f2bf(Wf[(l * 16 + 8 * h + j) * N_ + n]);
      bfr[l] = __builtin_bit_cast(bf16x8, u);
    }
  } else {
    #pragma unroll
    for (int l = 0; l < K_; ++l) {
      int n = wid * 32 + nl;
      bfr[l] = __builtin_bit_cast(bf16x8,
          *(const u16x8*)(Wb + ((l * N_ + n) * 16 + 8 * h)));
    }
  }

  const float* xrow = x + (size_t)(b * C_ + wid) * L_;  // wave wid stages channel wid

  #pragma unroll 1
  for (int it = 0; it < TPG; ++it) {
    const int tile = grp * TPG + it;
    const int t0   = tile * MT;     // base transition/position index

    __syncthreads();                // pairLds/xs no longer read by prev iter
    // ---- stage x: xs[c][u] = x[b,c,t0+u], u in [0,84) ----
    {
      int t = t0 + lane;
      xs[wid][lane] = (t < L_) ? xrow[t] : 0.f;
      if (lane < (ROWS + 1 - 64)) {                       // lane < 20
        int t2 = t0 + 64 + lane;
        xs[wid][64 + lane] = (t2 < L_) ? xrow[t2] : 0.f;
      }
    }
    __syncthreads();
    // ---- build pair tile: pair[r][i*4+j] = x[i][r]*x[j][r+1] (bf16) ----
    // 166 threads, each one half-row (8 products) -> one 16B LDS store
    if (tid < 2 * ROWS) {
      int r = tid >> 1, half = tid & 1;
      float x0 = xs[2 * half + 0][r], x1 = xs[2 * half + 1][r];
      float y0 = xs[0][r + 1], y1 = xs[1][r + 1];
      float y2 = xs[2][r + 1], y3 = xs[3][r + 1];
      u16x8 u;
      u[0] = f2bf(x0 * y0); u[1] = f2bf(x0 * y1);
      u[2] = f2bf(x0 * y2); u[3] = f2bf(x0 * y3);
      u[4] = f2bf(x1 * y0); u[5] = f2bf(x1 * y1);
      u[6] = f2bf(x1 * y2); u[7] = f2bf(x1 * y3);
      *(u16x8*)&pairLds[r * PSTR + 8 * half] = u;
    }
    __syncthreads();

    // ---- K loop: 20 x (2 ds_read_b128 + 2 mfma), W-stationary in VGPRs ----
    f32x16 acc0, acc1;
    #pragma unroll
    for (int i = 0; i < 16; ++i) { acc0[i] = 0.f; acc1[i] = 0.f; }

    #pragma unroll
    for (int l = 0; l < K_; ++l) {
      // B-fragment: B[k=8h+j][col=nl] = pair[pb*32 + nl + l][k]
      bf16x8 p0 = __builtin_bit_cast(bf16x8,
          *(const u16x8*)&pairLds[(nl + l) * PSTR + 8 * h]);
      bf16x8 p1 = __builtin_bit_cast(bf16x8,
          *(const u16x8*)&pairLds[(32 + nl + l) * PSTR + 8 * h]);
      acc0 = __builtin_amdgcn_mfma_f32_32x32x16_bf16(bfr[l], p0, acc0, 0, 0, 0);
      acc1 = __builtin_amdgcn_mfma_f32_32x32x16_bf16(bfr[l], p1, acc1, 0, 0, 0);
    }

    // ---- epilogue: D col = lane -> position, D rows = 16 n's.
    //      32 lanes store 128B contiguous per n-row: full lines, no scatter ----
    float* base = out + (size_t)(b * N_ + wid * 32 + 4 * h) * P_;
    {
      int p = t0 + nl;
      if (p < P_) {
        #pragma unroll
        for (int r = 0; r < 16; ++r) {
          int m = (r & 3) + 8 * (r >> 2);        // n offset within wave's block
          __builtin_nontemporal_store(acc0[r], base + (size_t)m * P_ + p);
        }
      }
      int p2 = t0 + 32 + nl;
      if (p2 < P_) {
        #pragma unroll
        for (int r = 0; r < 16; ++r) {
          int m = (r & 3) + 8 * (r >> 2);
          __builtin_nontemporal_store(acc1[r], base + (size_t)m * P_ + p2);
        }
      }
    }
  }
}

extern "C" void kernel_launch(void* const* d_in, const int* in_sizes, int n_in,
                              void* d_out, int out_size, void* d_ws, size_t ws_size,
                              hipStream_t stream) {
  const float* x  = (const float*)d_in[0];
  const float* W  = (const float*)d_in[1];
  float* out      = (float*)d_out;

  const size_t wbBytes = (size_t)K_ * N_ * 16 * sizeof(unsigned short); // 80 KB
  int useGather = (ws_size < wbBytes || d_ws == nullptr) ? 1 : 0;
  unsigned short* Wb = (unsigned short*)d_ws;

  if (!useGather) {
    convW_kernel<<<dim3((K_ * N_ * 16 + 255) / 256), dim3(256), 0, stream>>>(W, Wb);
  }
  markonv_kernel<<<dim3(GRPS, B_), dim3(256), 0, stream>>>(x, Wb, W, out, useGather);
}

// Round 2
// 911.628 us; speedup vs baseline: 1.7920x; 1.1250x over previous
//
#include <hip/hip_runtime.h>

// Markonv: out[b,n,p] = sum_{l,ij} x[b,i,p+l]*x[b,j,p+l+1] * W[l,i,j,n]
// B=128, C=4, L=10000, K=20, N=128, stride=1, P=9980.
// v3: mega-stage. v2 had 3 barriers x 13 tiles per WG; every tile put a global
// load latency + 2 LDS round-trips + vmcnt drain on the critical path =>
// MfmaUtil 8%, everything idle. Now: stage the WG's whole 768-position span
// once (xs 12.7 KB), build all 787 pair rows once (37.8 KB), then 12 MFMA
// tiles with ZERO barriers (waves drift, loads/MFMA/stores overlap).
// 2 barriers/WG instead of 36. LDS 50.6 KB -> 3 WGs/CU.
// Roofline: 654 MB fp32 output write ~190 us at NT-store BW; MFMA ~41 us.

#define B_    128
#define C_    4
#define L_    10000
#define K_    20
#define N_    128
#define P_    9980            // floor((L-1-K)/1)+1
#define MT    64              // output positions per tile
#define TPG   12              // tiles per workgroup
#define GRPS  13              // 13*12*64 = 9984 >= 9980
#define SPAN  (TPG * MT)      // 768 positions per WG
#define ROWS  (SPAN + K_ - 1) // 787 pair rows
#define XSL   (ROWS + 1)      // 788 x positions per channel
#define PSTR  24              // pair row stride in shorts (48 B -> 4-way banks)

typedef float  f32x16 __attribute__((ext_vector_type(16)));
typedef __bf16 bf16x8 __attribute__((ext_vector_type(8)));
typedef unsigned short u16x8 __attribute__((ext_vector_type(8)));

static __device__ __forceinline__ unsigned short f2bf(float f) {
  union { float f; unsigned u; } v; v.f = f;
  unsigned r = (v.u + 0x7fffu + ((v.u >> 16) & 1u)) >> 16;
  return (unsigned short)r;
}

// Repack W[l][i][j][n] fp32 -> Wb[l][n][ij] bf16 (A-fragment friendly: 16
// contiguous bf16 per (l,n) row = one 16B half per lane-half).
__global__ void convW_kernel(const float* __restrict__ W,
                             unsigned short* __restrict__ Wb) {
  int idx = blockIdx.x * 256 + threadIdx.x;          // [l][n][ij]
  if (idx < K_ * N_ * 16) {
    int ij = idx & 15, n = (idx >> 4) & (N_ - 1), l = idx >> 11;
    Wb[idx] = f2bf(W[(l * 16 + ij) * N_ + n]);
  }
}

template <int USE_GATHER>
__launch_bounds__(256, 3)
__global__ void markonv_kernel(const float* __restrict__ x,
                               const unsigned short* __restrict__ Wb,
                               const float* __restrict__ Wf,
                               float* __restrict__ out) {
  __shared__ __align__(16) float xs[C_][XSL + 4];                // 12.7 KB
  __shared__ __align__(16) unsigned short pairLds[ROWS * PSTR];  // 37.8 KB

  const int tid  = threadIdx.x;
  const int lane = tid & 63;
  const int wid  = tid >> 6;        // wave owns n-block: n = wid*32 + nl
  const int h    = lane >> 5;       // k-half
  const int nl   = lane & 31;
  const int b    = blockIdx.y;
  const int grp  = blockIdx.x;
  const int t0g  = grp * SPAN;

  // ---- W fragments (A-operand), 20 x 4 VGPR = 80, resident; branch-free ----
  // bfr[l]: lane holds W[l][k=8h+j][n = wid*32 + nl], j=0..7
  bf16x8 bfr[K_];
  if (USE_GATHER) {
    #pragma unroll
    for (int l = 0; l < K_; ++l) {
      int n = wid * 32 + nl;
      u16x8 u;
      #pragma unroll
      for (int j = 0; j < 8; ++j)
        u[j] = f2bf(Wf[(l * 16 + 8 * h + j) * N_ + n]);
      bfr[l] = __builtin_bit_cast(bf16x8, u);
    }
  } else {
    #pragma unroll
    for (int l = 0; l < K_; ++l) {
      int n = wid * 32 + nl;
      bfr[l] = __builtin_bit_cast(bf16x8,
          *(const u16x8*)(Wb + ((l * N_ + n) * 16 + 8 * h)));
    }
  }

  // ---- phase A: stage the whole span, wave wid = channel wid, float4 ----
  {
    const float* xrow = x + (size_t)(b * C_ + wid) * L_;
    #pragma unroll 1
    for (int v = lane; v < XSL / 4; v += 64) {          // 197 float4 chunks
      int t = t0g + 4 * v;
      float4 val;
      if (t + 3 < L_) {
        val = *(const float4*)(xrow + t);               // t0g%768==0 -> aligned
      } else {
        val.x = (t + 0 < L_) ? xrow[t + 0] : 0.f;
        val.y = (t + 1 < L_) ? xrow[t + 1] : 0.f;
        val.z = (t + 2 < L_) ? xrow[t + 2] : 0.f;
        val.w = (t + 3 < L_) ? xrow[t + 3] : 0.f;
      }
      *(float4*)&xs[wid][4 * v] = val;
    }
  }
  __syncthreads();

  // ---- phase B: build ALL pair rows: pair[r][i*4+j] = x[i][r]*x[j][r+1] ----
  // 1574 half-row tasks over 256 threads; one 16B LDS store per task
  #pragma unroll 1
  for (int task = tid; task < ROWS * 2; task += 256) {
    int r = task >> 1, half = task & 1;
    float x0 = xs[2 * half + 0][r], x1 = xs[2 * half + 1][r];
    float y0 = xs[0][r + 1], y1 = xs[1][r + 1];
    float y2 = xs[2][r + 1], y3 = xs[3][r + 1];
    u16x8 u;
    u[0] = f2bf(x0 * y0); u[1] = f2bf(x0 * y1);
    u[2] = f2bf(x0 * y2); u[3] = f2bf(x0 * y3);
    u[4] = f2bf(x1 * y0); u[5] = f2bf(x1 * y1);
    u[6] = f2bf(x1 * y2); u[7] = f2bf(x1 * y3);
    *(u16x8*)&pairLds[r * PSTR + 8 * half] = u;
  }
  __syncthreads();

  // ---- phase C: 12 tiles, NO barriers. W-stationary, pair read-only ----
  #pragma unroll 1
  for (int it = 0; it < TPG; ++it) {
    const int t0 = t0g + it * MT;
    f32x16 acc0, acc1;
    #pragma unroll
    for (int i = 0; i < 16; ++i) { acc0[i] = 0.f; acc1[i] = 0.f; }

    const int rbase = it * MT + nl;
    #pragma unroll
    for (int l = 0; l < K_; ++l) {
      bf16x8 p0 = __builtin_bit_cast(bf16x8,
          *(const u16x8*)&pairLds[(rbase + l) * PSTR + 8 * h]);
      bf16x8 p1 = __builtin_bit_cast(bf16x8,
          *(const u16x8*)&pairLds[(rbase + 32 + l) * PSTR + 8 * h]);
      acc0 = __builtin_amdgcn_mfma_f32_32x32x16_bf16(bfr[l], p0, acc0, 0, 0, 0);
      acc1 = __builtin_amdgcn_mfma_f32_32x32x16_bf16(bfr[l], p1, acc1, 0, 0, 0);
    }

    // epilogue: D col = lane -> position; 16 regs = 16 n-rows. r-major order
    // so each n-row gets 256B contiguous from this wave (L2 line merging).
    float* base = out + (size_t)(b * N_ + wid * 32 + 4 * h) * P_;
    const int p = t0 + nl, p2 = t0 + 32 + nl;
    #pragma unroll
    for (int r = 0; r < 16; ++r) {
      int m = (r & 3) + 8 * (r >> 2);        // n offset within wave's block
      float* orow = base + (size_t)m * P_;
      if (p < P_)  __builtin_nontemporal_store(acc0[r], orow + p);
      if (p2 < P_) __builtin_nontemporal_store(acc1[r], orow + p2);
    }
  }
}

extern "C" void kernel_launch(void* const* d_in, const int* in_sizes, int n_in,
                              void* d_out, int out_size, void* d_ws, size_t ws_size,
                              hipStream_t stream) {
  const float* x  = (const float*)d_in[0];
  const float* W  = (const float*)d_in[1];
  float* out      = (float*)d_out;

  const size_t wbBytes = (size_t)K_ * N_ * 16 * sizeof(unsigned short); // 80 KB
  int useGather = (ws_size < wbBytes || d_ws == nullptr) ? 1 : 0;
  unsigned short* Wb = (unsigned short*)d_ws;

  if (!useGather) {
    convW_kernel<<<dim3((K_ * N_ * 16 + 255) / 256), dim3(256), 0, stream>>>(W, Wb);
    markonv_kernel<0><<<dim3(GRPS, B_), dim3(256), 0, stream>>>(x, Wb, W, out);
  } else {
    markonv_kernel<1><<<dim3(GRPS, B_), dim3(256), 0, stream>>>(x, Wb, W, out);
  }
}